// Round 6
// baseline (549.402 us; speedup 1.0000x reference)
//
#include <hip/hip_runtime.h>
#include <hip/hip_bf16.h>
#include <cstdint>

// GraphSAGEMean: x = relu chain of 4 linears over N rows; agg = row-mean of E.
//
// R6 structure: persistent blocks (512 thr = 8 waves, 1 block/CU). Weights
// W1-W3 live in REGISTERS (192 VGPR/wave: wave owns 32 out-ch, 2 frags x 8
// k-steps x 4 VGPR x 3 layers), loaded ONCE per kernel and pinned with
// asm "+v" so the compiler cannot re-sink the loads (R2 failure mode).
// Wo in LDS (64KB, staged once). E prefetched one tile ahead into a 64KB
// LDS f32 buffer via global_load_lds, issued after phase0 -> hidden under
// the 4 MFMA layers. k-loop does ONLY 4 B-frag ds_read_b128 per 8 MFMAs.
// LDS = 32KB act + 64KB Wo + 64KB Estage = 163840 B exact fit.
//
// History: R0-R2 weights-from-global: latency-bound, 294-310us. R4 NT stores:
// FETCH x4, reverted. R5 weights-in-LDS: LDS-BW-bound (5 b128 reads per 4
// MFMA, bc cache didn't materialize, conflicts 20.8M), 303us. Constant:
// MfmaUtil*dur == 37us == MFMA floor -> feed the pipe from registers.

#define N_ROWS 200000
#define O_DIM  128
#define ROWS   64          // rows per tile; 3125 * 64 == 200000 exactly
#define NTILES 3125
#define GRIDP  256         // persistent blocks: 1 per CU

typedef short bf16x8 __attribute__((ext_vector_type(8)));   // 8 bf16 = 4 VGPRs
typedef float f32x4  __attribute__((ext_vector_type(4)));

__device__ __forceinline__ unsigned short rne_bf16(float f) {
  unsigned int u = __float_as_uint(f);
  u += 0x7FFFu + ((u >> 16) & 1u);      // round-to-nearest-even
  return (unsigned short)(u >> 16);
}

// XOR swizzle on byte offsets of 512B-row tiles (involution; XOR bits [6:4]
// from row bits [11:9], disjoint -> swz(swz(b)) == b).
__device__ __forceinline__ int swz(int b) { return b ^ (((b >> 9) & 7) << 4); }

// Transpose + bf16-cast all weights into ws: Wt[o][i] = bf16(W[i][o]).
// Layout (ushort elems): Wt1 @0, Wt2 @65536, Wt3 @131072, Wto @196608.
__global__ __launch_bounds__(256) void prep_kernel(
    const float* __restrict__ W1, const float* __restrict__ W2,
    const float* __restrict__ W3, const float* __restrict__ Wo,
    unsigned short* __restrict__ wt) {
  const int b = blockIdx.x;
  const int t = threadIdx.x;
  if (b < 256) {
    wt[b * 256 + t] = rne_bf16(W1[t * 256 + b]);
  } else if (b < 512) {
    const int o = b - 256;
    wt[65536 + o * 256 + t] = rne_bf16(W2[t * 256 + o]);
  } else if (b < 768) {
    const int o = b - 512;
    wt[131072 + o * 256 + t] = rne_bf16(W3[t * 256 + o]);
  } else {
    const int o = b - 768;
    wt[196608 + o * 256 + t] = rne_bf16(Wo[t * 128 + o]);
  }
}

__global__ __launch_bounds__(512, 2) void sage_kernel(
    const float* __restrict__ E,
    const float* __restrict__ b1, const float* __restrict__ b2,
    const float* __restrict__ b3, const float* __restrict__ bo,
    const unsigned short* __restrict__ wts,
    float* __restrict__ out_x, float* __restrict__ out_agg) {
  __shared__ __align__(16) unsigned short act[16384];    // 32 KB, swizzled bf16
  __shared__ __align__(16) unsigned short wo_l[32768];   // 64 KB, swizzled Wo
  __shared__ __align__(16) float est[16384];             // 64 KB, linear f32 E
  char* actb = (char*)act;

  const int t    = threadIdx.x;
  const int wave = t >> 6;          // 0..7
  const int lane = t & 63;
  const int lc   = lane & 15;
  const int quad = lane >> 4;

  // ---- one-time: W1-W3 fragments -> registers (192 VGPR), pinned ----
  bf16x8 wreg[3][2][8];
#pragma unroll
  for (int L = 0; L < 3; ++L)
#pragma unroll
    for (int mb = 0; mb < 2; ++mb)
#pragma unroll
      for (int ks = 0; ks < 8; ++ks)
        wreg[L][mb][ks] = *(const bf16x8*)&wts[L * 65536 +
            (wave * 32 + mb * 16 + lc) * 256 + ks * 32 + 8 * quad];
#pragma unroll
  for (int L = 0; L < 3; ++L)
#pragma unroll
    for (int mb = 0; mb < 2; ++mb)
#pragma unroll
      for (int ks = 0; ks < 8; ++ks)
        asm volatile("" : "+v"(wreg[L][mb][ks]));   // opaque: no remat/resink

  // ---- one-time: Wo -> LDS (linear dest + inverse-swizzled source) ----
  {
    const char* wsrc = (const char*)(wts + 196608);
#pragma unroll
    for (int rnd = 0; rnd < 8; ++rnd) {
      const int rel = rnd * 8192 + wave * 1024 + lane * 16;
      __builtin_amdgcn_global_load_lds(
          (const unsigned int*)(wsrc + swz(rel)),
          (unsigned int*)((char*)wo_l + rnd * 8192 + wave * 1024), 16, 0, 0);
    }
  }

  // E tile stage: 64 rows x 1KB, linear; wave w stages rows == w (mod 8).
  auto stageE = [&](int tl) {
    const char* src = (const char*)(E + (long)tl * ROWS * 256);
#pragma unroll
    for (int rnd = 0; rnd < 8; ++rnd) {
      const int rel = rnd * 8192 + wave * 1024 + lane * 16;
      __builtin_amdgcn_global_load_lds(
          (const unsigned int*)(src + rel),
          (unsigned int*)((char*)est + rnd * 8192 + wave * 1024), 16, 0, 0);
    }
  };

  // One 256->256 layer: A from wreg, B from act, out -> act (bias+relu+bf16).
  auto layer3 = [&](const bf16x8 (&wl)[2][8], const float* bias) {
    f32x4 acc[2][4];
#pragma unroll
    for (int mb = 0; mb < 2; ++mb)
#pragma unroll
      for (int nb = 0; nb < 4; ++nb)
        acc[mb][nb] = (f32x4){0.f, 0.f, 0.f, 0.f};
#pragma unroll
    for (int ks = 0; ks < 8; ++ks) {
      bf16x8 bfr[4];
#pragma unroll
      for (int nb = 0; nb < 4; ++nb)
        bfr[nb] = *(const bf16x8*)(actb +
                     swz((nb * 16 + lc) * 512 + ks * 64 + 16 * quad));
#pragma unroll
      for (int mb = 0; mb < 2; ++mb)
#pragma unroll
        for (int nb = 0; nb < 4; ++nb)
          acc[mb][nb] = __builtin_amdgcn_mfma_f32_16x16x32_bf16(
              wl[mb][ks], bfr[nb], acc[mb][nb], 0, 0, 0);
    }
    __syncthreads();   // all act reads done before overwrite
#pragma unroll
    for (int mb = 0; mb < 2; ++mb) {
      const int ch = wave * 32 + mb * 16 + 4 * quad;
      const f32x4 bb = *(const f32x4*)(bias + ch);
#pragma unroll
      for (int nb = 0; nb < 4; ++nb) {
        f32x4 v = acc[mb][nb] + bb;
#pragma unroll
        for (int j = 0; j < 4; ++j) v[j] = fmaxf(v[j], 0.f);
        const int r = nb * 16 + lc;
        ushort4 h;
        h.x = rne_bf16(v[0]); h.y = rne_bf16(v[1]);
        h.z = rne_bf16(v[2]); h.w = rne_bf16(v[3]);
        *(ushort4*)(actb + swz(r * 512 + ch * 2)) = h;
      }
    }
    __syncthreads();   // layer output visible
  };

  int tile = blockIdx.x;
  stageE(tile);        // tile 0 E; drains at first loop-top barrier

  for (;;) {
    const long row0 = (long)tile * ROWS;
    __syncthreads();   // Estage resident (barrier drains vmcnt); act free

    // ---- phase 0: Estage f32 -> act bf16 (swizzled) + fused row-mean ----
    {
      f32x4 st[8];
#pragma unroll
      for (int i = 0; i < 8; ++i)
        st[i] = *(const f32x4*)((const char*)est + (i * 8 + wave) * 1024 + lane * 16);
#pragma unroll
      for (int i = 0; i < 8; ++i) {
        const int r = i * 8 + wave;
        ushort4 h;
        h.x = rne_bf16(st[i][0]); h.y = rne_bf16(st[i][1]);
        h.z = rne_bf16(st[i][2]); h.w = rne_bf16(st[i][3]);
        *(ushort4*)(actb + swz(r * 512 + lane * 8)) = h;
        float s = st[i][0] + st[i][1] + st[i][2] + st[i][3];
        s += __shfl_down(s, 32);
        s += __shfl_down(s, 16);
        s += __shfl_down(s, 8);
        s += __shfl_down(s, 4);
        s += __shfl_down(s, 2);
        s += __shfl_down(s, 1);
        if (lane == 0) out_agg[row0 + r] = s * (1.0f / 256.0f);
      }
    }
    __syncthreads();   // act ready; all Estage reads retired (safe to refill)

    const int nxt = tile + GRIDP;
    const bool has_next = nxt < NTILES;
    if (has_next) stageE(nxt);      // flies under layers 1-4

    // ---- layers 1-3 (register-stationary weights) ----
    layer3(wreg[0], b1);
    layer3(wreg[1], b2);
    layer3(wreg[2], b3);

    // ---- layer 4: Wo from LDS, no relu, f32 store to out_x ----
    {
      f32x4 acc4[4];
#pragma unroll
      for (int nb = 0; nb < 4; ++nb) acc4[nb] = (f32x4){0.f, 0.f, 0.f, 0.f};
#pragma unroll
      for (int ks = 0; ks < 8; ++ks) {
        const bf16x8 afr = *(const bf16x8*)((char*)wo_l +
            swz((wave * 16 + lc) * 512 + ks * 64 + 16 * quad));
        bf16x8 bfr[4];
#pragma unroll
        for (int nb = 0; nb < 4; ++nb)
          bfr[nb] = *(const bf16x8*)(actb +
                       swz((nb * 16 + lc) * 512 + ks * 64 + 16 * quad));
#pragma unroll
        for (int nb = 0; nb < 4; ++nb)
          acc4[nb] = __builtin_amdgcn_mfma_f32_16x16x32_bf16(
              afr, bfr[nb], acc4[nb], 0, 0, 0);
      }
      const int ch = wave * 16 + 4 * quad;
      const f32x4 bb = *(const f32x4*)(bo + ch);
#pragma unroll
      for (int nb = 0; nb < 4; ++nb) {
        f32x4 v = acc4[nb] + bb;
        const long gr = row0 + nb * 16 + lc;
        *(f32x4*)&out_x[gr * O_DIM + ch] = v;
      }
    }

    if (!has_next) break;
    tile = nxt;
  }
}

extern "C" void kernel_launch(void* const* d_in, const int* in_sizes, int n_in,
                              void* d_out, int out_size, void* d_ws, size_t ws_size,
                              hipStream_t stream) {
  const float* E  = (const float*)d_in[0];
  // d_in[1] = adj_keys: mathematically unused (identity gather in reference)
  const float* W1 = (const float*)d_in[2];
  const float* b1 = (const float*)d_in[3];
  const float* W2 = (const float*)d_in[4];
  const float* b2 = (const float*)d_in[5];
  const float* W3 = (const float*)d_in[6];
  const float* b3 = (const float*)d_in[7];
  const float* Wo = (const float*)d_in[8];
  const float* bo = (const float*)d_in[9];

  float* out_x   = (float*)d_out;
  float* out_agg = out_x + (size_t)N_ROWS * O_DIM;
  unsigned short* wts = (unsigned short*)d_ws;   // 458752 B used

  prep_kernel<<<896, 256, 0, stream>>>(W1, W2, W3, Wo, wts);

  sage_kernel<<<GRIDP, 512, 0, stream>>>(E, b1, b2, b3, bo, wts, out_x, out_agg);
}